// Round 3
// baseline (83.404 us; speedup 1.0000x reference)
//
#include <hip/hip_runtime.h>
#include <math.h>

#define NCAND 75
#define NBT 8
#define NC 3
#define IMH 192
#define IMW 192
#define CROP 174
#define CH0 9
#define CW0 9
#define NPIX (CROP * CROP)          // 30276
#define CHW (IMH * IMW)             // 36864
#define IMG_STRIDE (NC * CHW)
#define DENOM 90828.0f              // NC * CROP * CROP
#define ROWS 6                      // rows per block
#define NCHUNK (CROP / ROWS)        // 29
#define NTHREADS 192
#define INV955 (1.0f / 95.5f)

// Interior-bounds proof: |t1|,|t2| <= 88.5; |awr|,|ahr| <= 88.5*(cos1+sin1) <= 90.03
// -> x,y in [4.97, 186.03] -> x0,y0 in [4,186], x1,y1 <= 187 < 192.
// So every bilinear corner is strictly in-bounds for ALL 75 candidates: no
// valid-masking or clamping needed.

// --- kernel 1: per-(cand, row-chunk) SAD partials for ALL 8 images ---------
// grid = dim3(NCAND, NCHUNK): cand is the FAST blockIdx dim so consecutive
// blocks (co-resident, round-robin across XCDs) share the same 6-row source
// slab -> L2-resident working set per XCD (~0.5 MB), unlike the chunk-fast
// order which thrashed L2 (FETCH 130 MB).
__global__ __launch_bounds__(NTHREADS) void sad_allimg_kernel(
        const float* __restrict__ img,
        const float* __restrict__ ref,
        float* __restrict__ part) {
    const int cand  = blockIdx.x;         // 0..74
    const int chunk = blockIdx.y;         // 0..28

    const int ih  = cand / 15;
    const int rem = cand % 15;
    const int iw  = rem / 3;
    const int ir  = rem % 3;

    const float ash  = (float)(2 - ih);
    const float asw  = (float)(2 - iw);
    const float arot = (float)(1 - ir) * 0.017453292519943295f;
    const float cr = cosf(arot);
    const float sr = sinf(arot);

    const int j = threadIdx.x;            // column in crop
    float acc[NBT];
#pragma unroll
    for (int im = 0; im < NBT; ++im) acc[im] = 0.0f;

    if (j < CROP) {
        const float t1 = ((float)(CW0 + j) + asw) - 95.5f;   // aw - cx (asc==1)

        for (int r = 0; r < ROWS; ++r) {
            const int i = chunk * ROWS + r;
            const float t2 = ((float)(CH0 + i) + ash) - 95.5f;  // ah - cy
            const float awr = cr * t1 - sr * t2;
            const float ahr = sr * t1 + cr * t2;
            const float gx = awr * INV955;
            const float gy = ahr * INV955;
            const float x = ((gx + 1.0f) * 192.0f - 1.0f) * 0.5f;
            const float y = ((gy + 1.0f) * 192.0f - 1.0f) * 0.5f;

            const float x0f = floorf(x);
            const float y0f = floorf(y);
            const float wx = x - x0f;
            const float wy = y - y0f;
            const int x0 = (int)x0f;
            const int y0 = (int)y0f;

            const float omwx = 1.0f - wx;
            const float omwy = 1.0f - wy;
            const float w00 = omwx * omwy;
            const float w10 = wx * omwy;
            const float w01 = omwx * wy;
            const float w11 = wx * wy;

            const int a00 = y0 * IMW + x0;                    // all corners in-bounds
            const int ra  = (CH0 + i) * IMW + (CW0 + j);

#pragma unroll
            for (int im = 0; im < NBT; ++im) {
                float s = 0.0f;
#pragma unroll
                for (int c = 0; c < NC; ++c) {
                    // uniform SGPR base + per-pixel VGPR offset; corner loads
                    // use immediate offsets 0/4/768/772
                    const float* __restrict__ p = img + (im * IMG_STRIDE + c * CHW) + a00;
                    const float* __restrict__ q = ref + (im * IMG_STRIDE + c * CHW) + ra;
                    const float v = w00 * p[0] + w10 * p[1] +
                                    w01 * p[IMW] + w11 * p[IMW + 1];
                    s += fabsf(v - q[0]);
                }
                acc[im] += s;
            }
        }
    }

    // reduce each image's accumulator across the block (3 waves)
    __shared__ float wsum[3][NBT];
    const int lane = threadIdx.x & 63;
    const int wid  = threadIdx.x >> 6;
#pragma unroll
    for (int im = 0; im < NBT; ++im) {
        float a = acc[im];
#pragma unroll
        for (int off = 32; off > 0; off >>= 1) a += __shfl_down(a, off, 64);
        if (lane == 0) wsum[wid][im] = a;
    }
    __syncthreads();
    if (threadIdx.x < NBT) {
        const int im = threadIdx.x;
        part[(cand * NCHUNK + chunk) * NBT + im] =
            wsum[0][im] + wsum[1][im] + wsum[2][im];
    }
}

// --- kernel 2: reduce chunks -> sad, then per-image argmin -----------------
__global__ __launch_bounds__(640) void finalize_ws(const float* __restrict__ part,
                                                   float* __restrict__ out) {
    __shared__ float sads[NCAND * NBT];
    const int t = threadIdx.x;
    if (t < NCAND * NBT) {
        const int cand = t / NBT;
        const int im   = t % NBT;
        float ssum = 0.0f;
        const float* p = part + cand * NCHUNK * NBT + im;
        for (int ch = 0; ch < NCHUNK; ++ch) ssum += p[ch * NBT];
        const float sv = ssum / DENOM;
        sads[t] = sv;
        out[t] = sv;
    }
    __syncthreads();
    if (t < NBT) {
        float best = sads[t];
        int bi = 0;
        for (int c2 = 1; c2 < NCAND; ++c2) {
            const float v = sads[c2 * NBT + t];
            if (v < best) { best = v; bi = c2; }   // strict <: first-min tie-break
        }
        const int i0 = bi / 15;
        const int r  = bi % 15;
        const int i1 = r / 3;
        const int i2 = r % 3;
        out[600 + 0 * NBT + t] = (float)i0;
        out[600 + 1 * NBT + t] = (float)i1;
        out[600 + 2 * NBT + t] = (float)i2;
        out[600 + 3 * NBT + t] = 0.0f;
    }
}

// ---------------- fallback (tiny ws): direct per-(cand,img) path -----------
__global__ __launch_bounds__(256) void sad_direct_kernel(const float* __restrict__ img,
                                                         const float* __restrict__ ref,
                                                         float* __restrict__ out) {
    const int ci  = blockIdx.x;
    const int cand = ci / NBT;
    const int im   = ci % NBT;
    const int ih  = cand / 15;
    const int rem = cand % 15;
    const int iw  = rem / 3;
    const int ir  = rem % 3;
    const float ash  = (float)(2 - ih);
    const float asw  = (float)(2 - iw);
    const float arot = (float)(1 - ir) * 0.017453292519943295f;
    const float cr = cosf(arot);
    const float sr = sinf(arot);
    const float* ib = img + im * IMG_STRIDE;
    const float* rb = ref + im * IMG_STRIDE;
    float acc = 0.0f;
    for (int p = (int)threadIdx.x; p < NPIX; p += 256) {
        const int i = p / CROP;
        const int j = p - i * CROP;
        const float t1 = ((float)(CW0 + j) + asw) - 95.5f;
        const float t2 = ((float)(CH0 + i) + ash) - 95.5f;
        const float awr = cr * t1 - sr * t2;
        const float ahr = sr * t1 + cr * t2;
        const float x = ((awr * INV955 + 1.0f) * 192.0f - 1.0f) * 0.5f;
        const float y = ((ahr * INV955 + 1.0f) * 192.0f - 1.0f) * 0.5f;
        const float x0f = floorf(x);
        const float y0f = floorf(y);
        const float wx = x - x0f;
        const float wy = y - y0f;
        const int x0 = (int)x0f, y0 = (int)y0f;
        const float omwx = 1.0f - wx;
        const float omwy = 1.0f - wy;
        const float w00 = omwx * omwy;
        const float w10 = wx * omwy;
        const float w01 = omwx * wy;
        const float w11 = wx * wy;
        const int a00 = y0 * IMW + x0;
        const int ra  = (CH0 + i) * IMW + (CW0 + j);
#pragma unroll
        for (int c = 0; c < NC; ++c) {
            const float* cb = ib + c * CHW + a00;
            const float v = w00 * cb[0] + w10 * cb[1] +
                            w01 * cb[IMW] + w11 * cb[IMW + 1];
            acc += fabsf(v - rb[c * CHW + ra]);
        }
    }
#pragma unroll
    for (int off = 32; off > 0; off >>= 1) acc += __shfl_down(acc, off, 64);
    __shared__ float wsum[4];
    const int lane = threadIdx.x & 63;
    const int wid  = threadIdx.x >> 6;
    if (lane == 0) wsum[wid] = acc;
    __syncthreads();
    if (threadIdx.x == 0)
        out[ci] = (wsum[0] + wsum[1] + wsum[2] + wsum[3]) / DENOM;
}

__global__ __launch_bounds__(64) void finalize_direct(float* __restrict__ out) {
    const int t = threadIdx.x;
    if (t < NBT) {
        float best = out[t];
        int bi = 0;
        for (int c2 = 1; c2 < NCAND; ++c2) {
            const float v = out[c2 * NBT + t];
            if (v < best) { best = v; bi = c2; }
        }
        const int i0 = bi / 15;
        const int r  = bi % 15;
        const int i1 = r / 3;
        const int i2 = r % 3;
        out[600 + 0 * NBT + t] = (float)i0;
        out[600 + 1 * NBT + t] = (float)i1;
        out[600 + 2 * NBT + t] = (float)i2;
        out[600 + 3 * NBT + t] = 0.0f;
    }
}

extern "C" void kernel_launch(void* const* d_in, const int* in_sizes, int n_in,
                              void* d_out, int out_size, void* d_ws, size_t ws_size,
                              hipStream_t stream) {
    const float* img = (const float*)d_in[0];
    const float* ref = (const float*)d_in[1];
    float* out = (float*)d_out;

    if (ws_size >= (size_t)(NCAND * NCHUNK * NBT * sizeof(float))) {
        float* part = (float*)d_ws;
        hipLaunchKernelGGL(sad_allimg_kernel, dim3(NCAND, NCHUNK), dim3(NTHREADS),
                           0, stream, img, ref, part);
        hipLaunchKernelGGL(finalize_ws, dim3(1), dim3(640), 0, stream, part, out);
    } else {
        hipLaunchKernelGGL(sad_direct_kernel, dim3(NCAND * NBT), dim3(256),
                           0, stream, img, ref, out);
        hipLaunchKernelGGL(finalize_direct, dim3(1), dim3(64), 0, stream, out);
    }
}

// Round 4
// 59.052 us; speedup vs baseline: 1.4124x; 1.4124x over previous
//
#include <hip/hip_runtime.h>
#include <math.h>

#define NCAND 75
#define NBT 8
#define NC 3
#define IMH 192
#define IMW 192
#define CROP 174
#define CH0 9
#define CW0 9
#define NPIX (CROP * CROP)          // 30276
#define CHW (IMH * IMW)             // 36864
#define IMG_STRIDE (NC * CHW)
#define DENOM 90828.0f              // NC * CROP * CROP
#define ROWS 6                      // crop rows per block
#define NCHUNK (CROP / ROWS)        // 29
#define CGRP 15                     // candidates per block
#define NCG (NCAND / CGRP)          // 5
#define SLABROWS 16                 // source rows staged (proof below)
#define NTHREADS 192
#define INV955 (1.0f / 95.5f)

// Bounds proof (all 75 cands): t1,t2 in [k-88.5, k-84.5]; |sin(1deg)*88.5| <= 1.545.
// y = (192/191)*ahr + 95.5  ->  y in [i+4.98, i+13.02+0.0052*i] (i<=173 -> <=+13.93)
// => y0 in [i0+4, i0+18], y1 <= i0+19: rows [i0+4, i0+20) = 16 rows suffice.
// Same for x: x0 >= 4, x1 <= 187 < 192. No masking/clamping needed anywhere.

// --- kernel 1: block = (cand-group, image, row-chunk); img slab in LDS -----
__global__ __launch_bounds__(NTHREADS) void sad_lds_kernel(
        const float* __restrict__ img,
        const float* __restrict__ ref,
        float* __restrict__ part) {
    const int cg    = blockIdx.x;         // 0..4   (fastest: shares slab)
    const int im    = blockIdx.y;         // 0..7
    const int chunk = blockIdx.z;         // 0..28
    const int i0    = chunk * ROWS;
    const int ybase = i0 + 4;
    const int tid   = threadIdx.x;
    const int j     = tid;                // crop column

    __shared__ float slab[NC * SLABROWS * IMW];   // 36864 B
    __shared__ float wsum[3];

    // ---- stage slab: 3ch x 16 rows x 192 cols, float4-coalesced ----
    {
        const float4* __restrict__ src = (const float4*)(img + im * IMG_STRIDE);
        float4* __restrict__ dst = (float4*)slab;
        // float4 units: per (c,rr): 48; total 3*16*48 = 2304; 192 thr -> 12 iters
#pragma unroll
        for (int k = tid; k < NC * SLABROWS * (IMW / 4); k += NTHREADS) {
            const int c   = k / (SLABROWS * (IMW / 4));
            const int rem = k - c * (SLABROWS * (IMW / 4));
            const int rr  = rem / (IMW / 4);
            const int c4  = rem - rr * (IMW / 4);
            dst[k] = src[c * (CHW / 4) + (ybase + rr) * (IMW / 4) + c4];
        }
    }

    // ---- ref pixels for this thread's column, kept in registers ----
    float refv[ROWS][NC];
    if (j < CROP) {
        const float* __restrict__ rb = ref + im * IMG_STRIDE;
#pragma unroll
        for (int r = 0; r < ROWS; ++r)
#pragma unroll
            for (int c = 0; c < NC; ++c)
                refv[r][c] = rb[c * CHW + (CH0 + i0 + r) * IMW + (CW0 + j)];
    }
    __syncthreads();

    const int lane = tid & 63;
    const int wid  = tid >> 6;

    for (int k = 0; k < CGRP; ++k) {
        const int cand = cg * CGRP + k;
        const int ih  = cand / 15;
        const int rem = cand % 15;
        const int iw  = rem / 3;
        const int ir  = rem % 3;

        const float ash  = (float)(2 - ih);
        const float asw  = (float)(2 - iw);
        const float arot = (float)(1 - ir) * 0.017453292519943295f;
        const float cr = cosf(arot);
        const float sr = sinf(arot);

        float acc = 0.0f;
        if (j < CROP) {
            const float t1 = ((float)(CW0 + j) + asw) - 95.5f;
            const float crt1 = cr * t1;
            const float srt1 = sr * t1;
#pragma unroll
            for (int r = 0; r < ROWS; ++r) {
                const int i = i0 + r;
                const float t2 = ((float)(CH0 + i) + ash) - 95.5f;
                const float awr = crt1 - sr * t2;
                const float ahr = srt1 + cr * t2;
                const float gx = awr * INV955;
                const float gy = ahr * INV955;
                const float x = ((gx + 1.0f) * 192.0f - 1.0f) * 0.5f;
                const float y = ((gy + 1.0f) * 192.0f - 1.0f) * 0.5f;

                const float x0f = floorf(x);
                const float y0f = floorf(y);
                const float wx = x - x0f;
                const float wy = y - y0f;
                const int x0 = (int)x0f;
                const int y0 = (int)y0f;

                const float omwx = 1.0f - wx;
                const float omwy = 1.0f - wy;
                const float w00 = omwx * omwy;
                const float w10 = wx * omwy;
                const float w01 = omwx * wy;
                const float w11 = wx * wy;

                // local slab coords; all in-bounds by the proof above
                const float* __restrict__ p0 =
                    &slab[(y0 - ybase) * IMW + x0];
#pragma unroll
                for (int c = 0; c < NC; ++c) {
                    const float* __restrict__ pc = p0 + c * (SLABROWS * IMW);
                    const float v = w00 * pc[0] + w10 * pc[1] +
                                    w01 * pc[IMW] + w11 * pc[IMW + 1];
                    acc += fabsf(v - refv[r][c]);
                }
            }
        }

        // block reduce (3 waves)
#pragma unroll
        for (int off = 32; off > 0; off >>= 1) acc += __shfl_down(acc, off, 64);
        if (lane == 0) wsum[wid] = acc;
        __syncthreads();
        if (tid == 0)
            part[(cand * NCHUNK + chunk) * NBT + im] =
                wsum[0] + wsum[1] + wsum[2];
        __syncthreads();
    }
}

// --- kernel 2: reduce chunks -> sad, then per-image argmin -----------------
__global__ __launch_bounds__(640) void finalize_ws(const float* __restrict__ part,
                                                   float* __restrict__ out) {
    __shared__ float sads[NCAND * NBT];
    const int t = threadIdx.x;
    if (t < NCAND * NBT) {
        const int cand = t / NBT;
        const int im   = t % NBT;
        float ssum = 0.0f;
        const float* p = part + cand * NCHUNK * NBT + im;
        for (int ch = 0; ch < NCHUNK; ++ch) ssum += p[ch * NBT];
        const float sv = ssum / DENOM;
        sads[t] = sv;
        out[t] = sv;
    }
    __syncthreads();
    if (t < NBT) {
        float best = sads[t];
        int bi = 0;
        for (int c2 = 1; c2 < NCAND; ++c2) {
            const float v = sads[c2 * NBT + t];
            if (v < best) { best = v; bi = c2; }   // strict <: first-min tie-break
        }
        const int i0 = bi / 15;
        const int r  = bi % 15;
        const int i1 = r / 3;
        const int i2 = r % 3;
        out[600 + 0 * NBT + t] = (float)i0;
        out[600 + 1 * NBT + t] = (float)i1;
        out[600 + 2 * NBT + t] = (float)i2;
        out[600 + 3 * NBT + t] = 0.0f;
    }
}

// ---------------- fallback (tiny ws): direct per-(cand,img) path -----------
__global__ __launch_bounds__(256) void sad_direct_kernel(const float* __restrict__ img,
                                                         const float* __restrict__ ref,
                                                         float* __restrict__ out) {
    const int ci  = blockIdx.x;
    const int cand = ci / NBT;
    const int im   = ci % NBT;
    const int ih  = cand / 15;
    const int rem = cand % 15;
    const int iw  = rem / 3;
    const int ir  = rem % 3;
    const float ash  = (float)(2 - ih);
    const float asw  = (float)(2 - iw);
    const float arot = (float)(1 - ir) * 0.017453292519943295f;
    const float cr = cosf(arot);
    const float sr = sinf(arot);
    const float* ib = img + im * IMG_STRIDE;
    const float* rb = ref + im * IMG_STRIDE;
    float acc = 0.0f;
    for (int p = (int)threadIdx.x; p < NPIX; p += 256) {
        const int i = p / CROP;
        const int j = p - i * CROP;
        const float t1 = ((float)(CW0 + j) + asw) - 95.5f;
        const float t2 = ((float)(CH0 + i) + ash) - 95.5f;
        const float awr = cr * t1 - sr * t2;
        const float ahr = sr * t1 + cr * t2;
        const float x = ((awr * INV955 + 1.0f) * 192.0f - 1.0f) * 0.5f;
        const float y = ((ahr * INV955 + 1.0f) * 192.0f - 1.0f) * 0.5f;
        const float x0f = floorf(x);
        const float y0f = floorf(y);
        const float wx = x - x0f;
        const float wy = y - y0f;
        const int x0 = (int)x0f, y0 = (int)y0f;
        const float omwx = 1.0f - wx;
        const float omwy = 1.0f - wy;
        const float w00 = omwx * omwy;
        const float w10 = wx * omwy;
        const float w01 = omwx * wy;
        const float w11 = wx * wy;
        const int a00 = y0 * IMW + x0;
        const int ra  = (CH0 + i) * IMW + (CW0 + j);
#pragma unroll
        for (int c = 0; c < NC; ++c) {
            const float* cb = ib + c * CHW + a00;
            const float v = w00 * cb[0] + w10 * cb[1] +
                            w01 * cb[IMW] + w11 * cb[IMW + 1];
            acc += fabsf(v - rb[c * CHW + ra]);
        }
    }
#pragma unroll
    for (int off = 32; off > 0; off >>= 1) acc += __shfl_down(acc, off, 64);
    __shared__ float wsum[4];
    const int lane = threadIdx.x & 63;
    const int wid  = threadIdx.x >> 6;
    if (lane == 0) wsum[wid] = acc;
    __syncthreads();
    if (threadIdx.x == 0)
        out[ci] = (wsum[0] + wsum[1] + wsum[2] + wsum[3]) / DENOM;
}

__global__ __launch_bounds__(64) void finalize_direct(float* __restrict__ out) {
    const int t = threadIdx.x;
    if (t < NBT) {
        float best = out[t];
        int bi = 0;
        for (int c2 = 1; c2 < NCAND; ++c2) {
            const float v = out[c2 * NBT + t];
            if (v < best) { best = v; bi = c2; }
        }
        const int i0 = bi / 15;
        const int r  = bi % 15;
        const int i1 = r / 3;
        const int i2 = r % 3;
        out[600 + 0 * NBT + t] = (float)i0;
        out[600 + 1 * NBT + t] = (float)i1;
        out[600 + 2 * NBT + t] = (float)i2;
        out[600 + 3 * NBT + t] = 0.0f;
    }
}

extern "C" void kernel_launch(void* const* d_in, const int* in_sizes, int n_in,
                              void* d_out, int out_size, void* d_ws, size_t ws_size,
                              hipStream_t stream) {
    const float* img = (const float*)d_in[0];
    const float* ref = (const float*)d_in[1];
    float* out = (float*)d_out;

    if (ws_size >= (size_t)(NCAND * NCHUNK * NBT * sizeof(float))) {
        float* part = (float*)d_ws;
        hipLaunchKernelGGL(sad_lds_kernel, dim3(NCG, NBT, NCHUNK), dim3(NTHREADS),
                           0, stream, img, ref, part);
        hipLaunchKernelGGL(finalize_ws, dim3(1), dim3(640), 0, stream, part, out);
    } else {
        hipLaunchKernelGGL(sad_direct_kernel, dim3(NCAND * NBT), dim3(256),
                           0, stream, img, ref, out);
        hipLaunchKernelGGL(finalize_direct, dim3(1), dim3(64), 0, stream, out);
    }
}